// Round 9
// baseline (353.970 us; speedup 1.0000x reference)
//
#include <hip/hip_runtime.h>
#include <hip/hip_bf16.h>
#include <stdint.h>

// Problem constants (match reference)
#define NN 50000      // nodes
#define NE 800000     // edges
#define NL 100000     // label edges
#define SLOTS 64      // padded-CSR slots/node (incl. appended self-loop)
#define PADROW 50000  // dedicated all-zero row index in every h slice

// Bucketed CSR build
#define NB 196        // dst-range buckets: bucket = dst >> 8 (256 nodes each)
#define BSH 8
#define BCAP 5376     // edges/bucket capacity; mean 4082 -> +20 sigma

// Sliced h layout: h[p][node][32] bf16, slice stride SL shorts (3.2MB/slice).
#define SL (50001u * 32u)

typedef __attribute__((ext_vector_type(8))) short bf16x8;   // MFMA A/B frag
typedef __attribute__((ext_vector_type(4))) float f32x4;    // MFMA C/D frag
typedef __attribute__((ext_vector_type(4))) unsigned int u32x4;

__device__ __forceinline__ float asf(unsigned int u) {
    union { unsigned int i; float f; } c; c.i = u; return c.f;
}
__device__ __forceinline__ float bflo(unsigned int x) { return asf(x << 16); }
__device__ __forceinline__ float bfhi(unsigned int x) { return asf(x & 0xffff0000u); }
__device__ __forceinline__ unsigned short f2bf(float f) {
    union { float f; unsigned int i; } c; c.f = f;
    unsigned int u = c.i + (0x7fffu + ((c.i >> 16) & 1u));
    return (unsigned short)(u >> 16);
}

// ---- P0: W transpose+convert to bf16 Wt[n][k]; zero cursors + pad rows ----
// R21: zeroes the 4 per-slice pad rows of bufH (row 50000 of each slice;
// h3's 2 slices alias slices 0,1 -> covered).
__global__ void k_wprep(const float* __restrict__ W1, const float* __restrict__ W2,
                        const float* __restrict__ W3, unsigned short* __restrict__ Wt,
                        int* __restrict__ cursor, unsigned short* __restrict__ bufH) {
    int idx = blockIdx.x * 256 + threadIdx.x;   // grid exactly 160
    if (idx < NB) cursor[idx] = 0;
    if (idx < 64) {                             // 4 slices x 16 u32 pad words
        int sl = idx >> 4, w = idx & 15;
        unsigned int* pw = (unsigned int*)(bufH + (size_t)sl * SL + (size_t)PADROW * 32);
        pw[w] = 0;
    }
    const float* W; unsigned short* O; int base, Mloc;
    if (idx < 16384)      { W = W1; O = Wt;         base = idx;         Mloc = 128; }
    else if (idx < 32768) { W = W2; O = Wt + 16384; base = idx - 16384; Mloc = 128; }
    else                  { W = W3; O = Wt + 32768; base = idx - 32768; Mloc = 64;  }
    int n = base >> 7, k = base & 127;
    O[base] = f2bf(W[k * Mloc + n]);
}

// ---- P1: bin edges by dst range (LDS histogram -> packed NT writes) ----
__global__ __launch_bounds__(256) void k_bin(
        const int* __restrict__ src, const int* __restrict__ dst,
        int* __restrict__ cursor, unsigned int* __restrict__ binbuf) {
    __shared__ int hcnt[NB];
    __shared__ int hbase[NB];
    __shared__ unsigned int epk[2048];
    int tid = threadIdx.x;
    if (tid < NB) hcnt[tid] = 0;
    __syncthreads();
    int e0 = blockIdx.x * 2048;                 // grid exactly 391
    int e1 = min(e0 + 2048, NE);
    for (int e = e0 + tid; e < e1; e += 256) {
        int d = dst[e], s = src[e];
        atomicAdd(&hcnt[d >> BSH], 1);
        epk[e - e0] = (unsigned int)s | ((unsigned int)d << 16);
    }
    __syncthreads();
    if (tid < NB) { hbase[tid] = atomicAdd(&cursor[tid], hcnt[tid]); hcnt[tid] = 0; }
    __syncthreads();
    for (int e = e0 + tid; e < e1; e += 256) {
        unsigned int pk = epk[e - e0];
        int b = (int)(pk >> 16) >> BSH;
        int p = hbase[b] + atomicAdd(&hcnt[b], 1);
        if (p < BCAP)
            __builtin_nontemporal_store(pk, &binbuf[(size_t)b * BCAP + p]);
    }
}

// ---- P2: per-bucket CSR build in LDS + coalesced flush ----
// R21: IDENTITY slot layout (perm32 removed -- slice gather takes contiguous
// 16-slot batches). Pad slots = PADROW (zero row, mask-free); self-loop
// appended at slot p=deg.
__global__ __launch_bounds__(256) void k_csr(
        const unsigned int* __restrict__ binbuf, const int* __restrict__ cursor,
        int* __restrict__ deg, unsigned short* __restrict__ colp) {
    __shared__ unsigned short lcol[256 * SLOTS];   // 32 KB
    __shared__ int ldeg[256];
    int tid = threadIdx.x;
    int blk = blockIdx.x;                          // grid exactly NB
    int base = blk << BSH;
    int nNodes = min(256, NN - base);
    ldeg[tid] = 0;
    const unsigned int fw = 0xC350C350u;           // 2x 50000
    u32x4 fill = {fw, fw, fw, fw};
    u32x4* lz = (u32x4*)lcol;
#pragma unroll
    for (int i = 0; i < 8; ++i) lz[i * 256 + tid] = fill;
    __syncthreads();
    int cnt = min(cursor[blk], BCAP);
    for (int e = tid; e < cnt; e += 256) {
        unsigned int pk = __builtin_nontemporal_load(&binbuf[(size_t)blk * BCAP + e]);
        int d = (int)(pk >> 16) - base;
        int p = atomicAdd(&ldeg[d], 1);
        if (p < SLOTS) lcol[d * SLOTS + p] = (unsigned short)(pk & 0xffffu);
    }
    __syncthreads();
    if (tid < nNodes) {
        int dv = ldeg[tid];
        deg[base + tid] = dv;
        if (dv < SLOTS)                            // append self-loop slot
            lcol[tid * SLOTS + dv] = (unsigned short)(base + tid);
    }
    __syncthreads();
    u32x4* gout = (u32x4*)(colp + (size_t)base * SLOTS);
    const u32x4* lin = (const u32x4*)lcol;
    for (int i = tid; i < nNodes * 8; i += 256) gout[i] = lin[i];
}

// ---- layer-1 GEMM: x (fp32) -> bufH (h1, SLICED layout) ----
// store col = t*16+m -> slice t>>1, offset (t&1)*16+m.
__global__ __launch_bounds__(256) void k_gemm1(
        const float* __restrict__ A, const unsigned short* __restrict__ Wt,
        const int* __restrict__ deg, unsigned short* __restrict__ Outb, int N) {
    constexpr int K = 128;
    constexpr int NT = 8;
    int tid = threadIdx.x;
    int lane = tid & 63, wave = tid >> 6;
    int m = lane & 15, quad = lane >> 4;
    int rowA = blockIdx.x * 64 + wave * 16 + m;    // grid exactly 782
    int rA = min(rowA, N - 1);

    bf16x8 afr[4];
    const float* p = A + (size_t)rA * K + quad * 8;
#pragma unroll
    for (int s = 0; s < 4; ++s) {
        float4 lo = *(const float4*)(p + s * 32);
        float4 hi = *(const float4*)(p + s * 32 + 4);
        bf16x8 r;
        r[0] = (short)f2bf(lo.x); r[1] = (short)f2bf(lo.y);
        r[2] = (short)f2bf(lo.z); r[3] = (short)f2bf(lo.w);
        r[4] = (short)f2bf(hi.x); r[5] = (short)f2bf(hi.y);
        r[6] = (short)f2bf(hi.z); r[7] = (short)f2bf(hi.w);
        afr[s] = r;
    }

    f32x4 acc[NT];
#pragma unroll
    for (int t = 0; t < NT; ++t) { acc[t][0] = 0.f; acc[t][1] = 0.f; acc[t][2] = 0.f; acc[t][3] = 0.f; }
#pragma unroll
    for (int t = 0; t < NT; ++t) {
        const unsigned short* wp = Wt + (size_t)(t * 16 + m) * K + quad * 8;
#pragma unroll
        for (int s = 0; s < 4; ++s) {
            bf16x8 bfr = *(const bf16x8*)(wp + s * 32);
            acc[t] = __builtin_amdgcn_mfma_f32_16x16x32_bf16(afr[s], bfr, acc[t], 0, 0, 0);
        }
    }

    int outRowBase = blockIdx.x * 64 + wave * 16 + quad * 4;
    float di[4];
#pragma unroll
    for (int i = 0; i < 4; ++i) di[i] = rsqrtf((float)deg[min(outRowBase + i, N - 1)] + 1.0f);
#pragma unroll
    for (int t = 0; t < NT; ++t)
#pragma unroll
        for (int i = 0; i < 4; ++i) {
            int rr = outRowBase + i;
            if (rr < N)
                Outb[(size_t)(t >> 1) * SL + (size_t)rr * 32 + (t & 1) * 16 + m] =
                    f2bf(acc[t][i] * di[i]);
        }
}

// ---- bf16 GEMM: z (row-major, K=128) -> bufH (sliced, M_ cols) ----
template <int M_>
__global__ __launch_bounds__(256) void k_gemmb(
        const unsigned short* __restrict__ A, const unsigned short* __restrict__ Wt,
        const int* __restrict__ deg, unsigned short* __restrict__ Outb, int N) {
    constexpr int K = 128;
    constexpr int NT = M_ / 16;
    int tid = threadIdx.x;
    int lane = tid & 63, wave = tid >> 6;
    int m = lane & 15, quad = lane >> 4;
    int rowA = blockIdx.x * 64 + wave * 16 + m;    // grid exactly 782
    int rA = min(rowA, N - 1);

    bf16x8 afr[4];
#pragma unroll
    for (int s = 0; s < 4; ++s)
        afr[s] = *(const bf16x8*)(A + (size_t)rA * K + quad * 8 + s * 32);

    f32x4 acc[NT];
#pragma unroll
    for (int t = 0; t < NT; ++t) { acc[t][0] = 0.f; acc[t][1] = 0.f; acc[t][2] = 0.f; acc[t][3] = 0.f; }
#pragma unroll
    for (int t = 0; t < NT; ++t) {
        const unsigned short* wp = Wt + (size_t)(t * 16 + m) * K + quad * 8;
#pragma unroll
        for (int s = 0; s < 4; ++s) {
            bf16x8 bfr = *(const bf16x8*)(wp + s * 32);
            acc[t] = __builtin_amdgcn_mfma_f32_16x16x32_bf16(afr[s], bfr, acc[t], 0, 0, 0);
        }
    }

    int outRowBase = blockIdx.x * 64 + wave * 16 + quad * 4;
    float di[4];
#pragma unroll
    for (int i = 0; i < 4; ++i) di[i] = rsqrtf((float)deg[min(outRowBase + i, N - 1)] + 1.0f);
#pragma unroll
    for (int t = 0; t < NT; ++t)
#pragma unroll
        for (int i = 0; i < 4; ++i) {
            int rr = outRowBase + i;
            if (rr < N)
                Outb[(size_t)(t >> 1) * SL + (size_t)rr * 32 + (t & 1) * 16 + m] =
                    f2bf(acc[t][i] * di[i]);
        }
}

// ---- R21 sliced aggregation: z[:, 32p:32p+32] = act(dinv*agg + b) ----
// slice p = blockIdx/3125: all ~2048 concurrently-resident blocks gather
// from the SAME contiguous 3.2MB slice -> L2-resident (per-XCD 4MB), only
// compulsory misses go to HBM/L3. Wave = 16 rows x 4 lanes (16B each);
// 2 batches/node cover 32 slots mask-free (pads read the zero row); 8
// independent gathers issued per wave. No LDS, no MFMA (no VGPR squeeze).
template <int NS, bool RELU>
__global__ __launch_bounds__(256) void k_aggs(
        const unsigned short* __restrict__ hsl, const int* __restrict__ deg,
        const unsigned short* __restrict__ colp, const float* __restrict__ bias,
        unsigned short* __restrict__ z) {
    constexpr int ZW = NS * 32;
    int tid = threadIdx.x;
    int wave = tid >> 6, lane = tid & 63;
    int r4 = lane >> 2, c4 = lane & 3;
    int p = blockIdx.x / 3125;                   // grid exactly NS*3125
    int tb = (blockIdx.x % 3125) * 16;
    int nodeB = tb + wave * 4;
    const unsigned short* hp = hsl + (size_t)p * SL;

    int4 dg = *(const int4*)(deg + nodeB);
    int dgv[4] = {dg.x, dg.y, dg.z, dg.w};

    float bb[8];
    {
        const float4* bp = (const float4*)(bias + p * 32 + c4 * 8);
        float4 b0 = bp[0], b1 = bp[1];
        bb[0] = b0.x; bb[1] = b0.y; bb[2] = b0.z; bb[3] = b0.w;
        bb[4] = b1.x; bb[5] = b1.y; bb[6] = b1.z; bb[7] = b1.w;
    }

    // slot indices: lane's row for (node t, batch b) = physical slot b*16+r4
    unsigned int idx[8];
#pragma unroll
    for (int t = 0; t < 4; ++t)
#pragma unroll
        for (int b = 0; b < 2; ++b)
            idx[t * 2 + b] = colp[(unsigned)(nodeB + t) * SLOTS + b * 16 + r4];

    // 8 independent gathers (16 rows x 64B-slice each)
    u32x4 v[8];
#pragma unroll
    for (int j = 0; j < 8; ++j)
        v[j] = *(const u32x4*)(hp + (size_t)idx[j] * 32 + c4 * 8);

#pragma unroll
    for (int t = 0; t < 4; ++t) {
        int node = nodeB + t;
        float acc[8];
#pragma unroll
        for (int k = 0; k < 8; ++k) acc[k] = 0.f;
#pragma unroll
        for (int b = 0; b < 2; ++b)
#pragma unroll
            for (int k = 0; k < 4; ++k) {
                acc[2 * k]     += bflo(v[t * 2 + b][k]);
                acc[2 * k + 1] += bfhi(v[t * 2 + b][k]);
            }
        if (dgv[t] > 31) {      // rare tail: slots 32..63 (pads = zero row)
#pragma unroll
            for (int b = 2; b < 4; ++b) {
                unsigned int ix = colp[(unsigned)node * SLOTS + b * 16 + r4];
                u32x4 w = *(const u32x4*)(hp + (size_t)ix * 32 + c4 * 8);
#pragma unroll
                for (int k = 0; k < 4; ++k) {
                    acc[2 * k]     += bflo(w[k]);
                    acc[2 * k + 1] += bfhi(w[k]);
                }
            }
        }
        // reduce over the 16 row-lanes (bits 2..5 of lane)
#pragma unroll
        for (int k = 0; k < 8; ++k) {
            acc[k] += __shfl_xor(acc[k], 4, 64);
            acc[k] += __shfl_xor(acc[k], 8, 64);
            acc[k] += __shfl_xor(acc[k], 16, 64);
            acc[k] += __shfl_xor(acc[k], 32, 64);
        }
        if (r4 == 0) {
            float di = rsqrtf((float)dgv[t] + 1.0f);
            u32x4 pv;
#pragma unroll
            for (int k = 0; k < 4; ++k) {
                float o0 = di * acc[2 * k]     + bb[2 * k];
                float o1 = di * acc[2 * k + 1] + bb[2 * k + 1];
                if (RELU) { o0 = fmaxf(o0, 0.f); o1 = fmaxf(o1, 0.f); }
                pv[k] = (unsigned int)f2bf(o0) | ((unsigned int)f2bf(o1) << 16);
            }
            *(u32x4*)(z + (size_t)node * ZW + p * 32 + c4 * 8) = pv;
        }
    }
}

// ---- decode: out[e] = dot(z[ls[e]], z[ld[e]]) over 64 dims, z bf16 ----
__global__ __launch_bounds__(256) void k_decode(
        const unsigned short* __restrict__ z, const int* __restrict__ ls,
        const int* __restrict__ ld, float* __restrict__ out, int nl) {
    int tid = threadIdx.x;
    int lane = tid & 63, wave = tid >> 6;
    int g = lane >> 3, c = lane & 7;
    int e = (blockIdx.x * 4 + wave) * 4 + (g >> 1);   // grid exactly 6250
    int row = (g & 1) ? ld[e] : ls[e];
    u32x4 v = *(const u32x4*)(z + (size_t)row * 64 + c * 8);
    u32x4 w;
#pragma unroll
    for (int k = 0; k < 4; ++k) w[k] = (unsigned int)__shfl_xor((int)v[k], 8, 64);
    float p = 0.f;
#pragma unroll
    for (int k = 0; k < 4; ++k)
        p += bflo(v[k]) * bflo(w[k]) + bfhi(v[k]) * bfhi(w[k]);
    p += __shfl_xor(p, 1, 64);
    p += __shfl_xor(p, 2, 64);
    p += __shfl_xor(p, 4, 64);
    if ((lane & 15) == 0) out[e] = p;   // lane in {0,16,32,48}: g even, c==0
}

// ================= launcher =================

static inline size_t align256(size_t x) { return (x + 255) & ~(size_t)255; }

extern "C" void kernel_launch(void* const* d_in, const int* in_sizes, int n_in,
                              void* d_out, int out_size, void* d_ws, size_t ws_size,
                              hipStream_t stream) {
    const float* x  = (const float*)d_in[0];
    const int*   ei = (const int*)d_in[1];    // [2][NE]: row0=src, row1=dst
    const int*   li = (const int*)d_in[2];    // [2][NL]
    const float* W1 = (const float*)d_in[3];
    const float* b1 = (const float*)d_in[4];
    const float* W2 = (const float*)d_in[5];
    const float* b2 = (const float*)d_in[6];
    const float* W3 = (const float*)d_in[7];
    const float* b3 = (const float*)d_in[8];
    float* out = (float*)d_out;

    const int* src = ei;
    const int* dst = ei + NE;
    const int* ls = li;
    const int* ld = li + NL;

    // workspace carve-up (~43 MB)
    char* ws = (char*)d_ws;
    size_t off = 0;
    int* deg    = (int*)(ws + off); off += align256(NN * 4);
    int* cursor = (int*)(ws + off); off += align256(NB * 4);
    unsigned int* binbuf = (unsigned int*)(ws + off); off += align256((size_t)NB * BCAP * 4);
    unsigned short* colp = (unsigned short*)(ws + off); off += align256((size_t)NN * SLOTS * 2);
    unsigned short* Wtb  = (unsigned short*)(ws + off); off += align256(40960 * 2);
    unsigned short* bufH = (unsigned short*)(ws + off); off += align256((size_t)4 * SL * 2);
    unsigned short* bufZ1 = (unsigned short*)(ws + off); off += align256((size_t)NN * 128 * 2);
    unsigned short* bufZZ = (unsigned short*)(ws + off); off += align256((size_t)NN * 64 * 2);

    // ---- CSR build + W prep (+ zero per-slice pad rows of bufH) ----
    k_wprep<<<160, 256, 0, stream>>>(W1, W2, W3, Wtb, cursor, bufH);
    k_bin<<<391, 256, 0, stream>>>(src, dst, cursor, binbuf);
    k_csr<<<NB, 256, 0, stream>>>(binbuf, cursor, deg, colp);

    // ---- layer 1: h1 = dinv * x@W1 (sliced) ----
    k_gemm1<<<782, 256, 0, stream>>>(x, Wtb, deg, bufH, NN);
    // ---- agg1: z1 = relu(dinv*agg(h1) + b1), L2-resident sliced gather ----
    k_aggs<4, true><<<12500, 256, 0, stream>>>(bufH, deg, colp, b1, bufZ1);
    // ---- layer 2: h2 = dinv * z1@W2 (sliced, overwrites bufH) ----
    k_gemmb<128><<<782, 256, 0, stream>>>(bufZ1, Wtb + 16384, deg, bufH, NN);
    // ---- agg2: z2 = relu(dinv*agg(h2) + b2) (overwrites bufZ1) ----
    k_aggs<4, true><<<12500, 256, 0, stream>>>(bufH, deg, colp, b2, bufZ1);
    // ---- layer 3: h3 = dinv * z2@W3 (2 slices into bufH slices 0,1) ----
    k_gemmb<64><<<782, 256, 0, stream>>>(bufZ1, Wtb + 32768, deg, bufH, NN);
    // ---- agg3: z = dinv*agg(h3) + b3 (no relu) ----
    k_aggs<2, false><<<6250, 256, 0, stream>>>(bufH, deg, colp, b3, bufZZ);
    // ---- decode ----
    k_decode<<<6250, 256, 0, stream>>>(bufZZ, ls, ld, out, NL);
}

// Round 11
// 289.953 us; speedup vs baseline: 1.2208x; 1.2208x over previous
//
#include <hip/hip_runtime.h>
#include <hip/hip_bf16.h>
#include <stdint.h>

// Problem constants (match reference)
#define NN 50000      // nodes
#define NE 800000     // edges
#define NL 100000     // label edges
#define SLOTS 64      // padded-CSR slots/node (incl. appended self-loop)
#define PADROW 50000  // dedicated all-zero row index in every h slice

// Bucketed CSR build
#define NB 196        // dst-range buckets: bucket = dst >> 8 (256 nodes each)
#define BSH 8
#define BCAP 5376     // edges/bucket capacity; mean 4082 -> +20 sigma

// Sliced h layout: h[p][node][32] bf16, slice stride SL shorts (3.2MB/slice).
#define SL (50001u * 32u)

typedef __attribute__((ext_vector_type(8))) short bf16x8;   // MFMA A/B frag
typedef __attribute__((ext_vector_type(4))) float f32x4;    // MFMA C/D frag
typedef __attribute__((ext_vector_type(4))) unsigned int u32x4;
typedef __attribute__((ext_vector_type(4))) int i32x4;
typedef __attribute__((ext_vector_type(8))) unsigned short u16x8;

__device__ __forceinline__ float asf(unsigned int u) {
    union { unsigned int i; float f; } c; c.i = u; return c.f;
}
__device__ __forceinline__ float bflo(unsigned int x) { return asf(x << 16); }
__device__ __forceinline__ float bfhi(unsigned int x) { return asf(x & 0xffff0000u); }
__device__ __forceinline__ unsigned short f2bf(float f) {
    union { float f; unsigned int i; } c; c.f = f;
    unsigned int u = c.i + (0x7fffu + ((c.i >> 16) & 1u));
    return (unsigned short)(u >> 16);
}

// ---- P0: W transpose+convert to bf16 Wt[n][k]; zero cursors + pad rows ----
__global__ void k_wprep(const float* __restrict__ W1, const float* __restrict__ W2,
                        const float* __restrict__ W3, unsigned short* __restrict__ Wt,
                        int* __restrict__ cursor, unsigned short* __restrict__ bufH) {
    int idx = blockIdx.x * 256 + threadIdx.x;   // grid exactly 160
    if (idx < NB) cursor[idx] = 0;
    if (idx < 64) {                             // 4 slices x 16 u32 pad words
        int sl = idx >> 4, w = idx & 15;
        unsigned int* pw = (unsigned int*)(bufH + (size_t)sl * SL + (size_t)PADROW * 32);
        pw[w] = 0;
    }
    const float* W; unsigned short* O; int base, Mloc;
    if (idx < 16384)      { W = W1; O = Wt;         base = idx;         Mloc = 128; }
    else if (idx < 32768) { W = W2; O = Wt + 16384; base = idx - 16384; Mloc = 128; }
    else                  { W = W3; O = Wt + 32768; base = idx - 32768; Mloc = 64;  }
    int n = base >> 7, k = base & 127;
    O[base] = f2bf(W[k * Mloc + n]);
}

// ---- P1: bin edges by dst range (LDS histogram -> packed NT writes) ----
__global__ __launch_bounds__(256) void k_bin(
        const int* __restrict__ src, const int* __restrict__ dst,
        int* __restrict__ cursor, unsigned int* __restrict__ binbuf) {
    __shared__ int hcnt[NB];
    __shared__ int hbase[NB];
    __shared__ unsigned int epk[2048];
    int tid = threadIdx.x;
    if (tid < NB) hcnt[tid] = 0;
    __syncthreads();
    int e0 = blockIdx.x * 2048;                 // grid exactly 391
    int e1 = min(e0 + 2048, NE);
    for (int e = e0 + tid; e < e1; e += 256) {
        int d = dst[e], s = src[e];
        atomicAdd(&hcnt[d >> BSH], 1);
        epk[e - e0] = (unsigned int)s | ((unsigned int)d << 16);
    }
    __syncthreads();
    if (tid < NB) { hbase[tid] = atomicAdd(&cursor[tid], hcnt[tid]); hcnt[tid] = 0; }
    __syncthreads();
    for (int e = e0 + tid; e < e1; e += 256) {
        unsigned int pk = epk[e - e0];
        int b = (int)(pk >> 16) >> BSH;
        int p = hbase[b] + atomicAdd(&hcnt[b], 1);
        if (p < BCAP)
            __builtin_nontemporal_store(pk, &binbuf[(size_t)b * BCAP + p]);
    }
}

// ---- P2: per-bucket CSR build in LDS + coalesced flush ----
// perm32: logical slot s<32 at physical 8*(s&3)+(s>>2), so physical
// [r*8, r*8+8) (r=0..3) holds logical {4k+r}: the agg's lane r4 reads its
// 8 slot-indices with ONE u16x8 load. Slots >=32 identity. Pads = PADROW
// (zero row, mask-free). Self-loop appended at logical slot p=deg.
__global__ __launch_bounds__(256) void k_csr(
        const unsigned int* __restrict__ binbuf, const int* __restrict__ cursor,
        int* __restrict__ deg, unsigned short* __restrict__ colp) {
    __shared__ unsigned short lcol[256 * SLOTS];   // 32 KB
    __shared__ int ldeg[256];
    int tid = threadIdx.x;
    int blk = blockIdx.x;                          // grid exactly NB
    int base = blk << BSH;
    int nNodes = min(256, NN - base);
    ldeg[tid] = 0;
    const unsigned int fw = 0xC350C350u;           // 2x 50000
    u32x4 fill = {fw, fw, fw, fw};
    u32x4* lz = (u32x4*)lcol;
#pragma unroll
    for (int i = 0; i < 8; ++i) lz[i * 256 + tid] = fill;
    __syncthreads();
    int cnt = min(cursor[blk], BCAP);
    for (int e = tid; e < cnt; e += 256) {
        unsigned int pk = __builtin_nontemporal_load(&binbuf[(size_t)blk * BCAP + e]);
        int d = (int)(pk >> 16) - base;
        int p = atomicAdd(&ldeg[d], 1);
        if (p < SLOTS) {
            int pp = (p < 32) ? ((p & 3) * 8 + (p >> 2)) : p;
            lcol[d * SLOTS + pp] = (unsigned short)(pk & 0xffffu);
        }
    }
    __syncthreads();
    if (tid < nNodes) {
        int dv = ldeg[tid];
        deg[base + tid] = dv;
        if (dv < SLOTS) {                          // append self-loop slot
            int pp = (dv < 32) ? ((dv & 3) * 8 + (dv >> 2)) : dv;
            lcol[tid * SLOTS + pp] = (unsigned short)(base + tid);
        }
    }
    __syncthreads();
    u32x4* gout = (u32x4*)(colp + (size_t)base * SLOTS);
    const u32x4* lin = (const u32x4*)lcol;
    for (int i = tid; i < nNodes * 8; i += 256) gout[i] = lin[i];
}

// ---- layer-1 GEMM: x (fp32) -> bufH (h1, SLICED layout) ----
__global__ __launch_bounds__(256) void k_gemm1(
        const float* __restrict__ A, const unsigned short* __restrict__ Wt,
        const int* __restrict__ deg, unsigned short* __restrict__ Outb, int N) {
    constexpr int K = 128;
    constexpr int NT = 8;
    int tid = threadIdx.x;
    int lane = tid & 63, wave = tid >> 6;
    int m = lane & 15, quad = lane >> 4;
    int rowA = blockIdx.x * 64 + wave * 16 + m;    // grid exactly 782
    int rA = min(rowA, N - 1);

    bf16x8 afr[4];
    const float* p = A + (size_t)rA * K + quad * 8;
#pragma unroll
    for (int s = 0; s < 4; ++s) {
        float4 lo = *(const float4*)(p + s * 32);
        float4 hi = *(const float4*)(p + s * 32 + 4);
        bf16x8 r;
        r[0] = (short)f2bf(lo.x); r[1] = (short)f2bf(lo.y);
        r[2] = (short)f2bf(lo.z); r[3] = (short)f2bf(lo.w);
        r[4] = (short)f2bf(hi.x); r[5] = (short)f2bf(hi.y);
        r[6] = (short)f2bf(hi.z); r[7] = (short)f2bf(hi.w);
        afr[s] = r;
    }

    f32x4 acc[NT];
#pragma unroll
    for (int t = 0; t < NT; ++t) { acc[t][0] = 0.f; acc[t][1] = 0.f; acc[t][2] = 0.f; acc[t][3] = 0.f; }
#pragma unroll
    for (int t = 0; t < NT; ++t) {
        const unsigned short* wp = Wt + (size_t)(t * 16 + m) * K + quad * 8;
#pragma unroll
        for (int s = 0; s < 4; ++s) {
            bf16x8 bfr = *(const bf16x8*)(wp + s * 32);
            acc[t] = __builtin_amdgcn_mfma_f32_16x16x32_bf16(afr[s], bfr, acc[t], 0, 0, 0);
        }
    }

    int outRowBase = blockIdx.x * 64 + wave * 16 + quad * 4;
    float di[4];
#pragma unroll
    for (int i = 0; i < 4; ++i) di[i] = rsqrtf((float)deg[min(outRowBase + i, N - 1)] + 1.0f);
#pragma unroll
    for (int t = 0; t < NT; ++t)
#pragma unroll
        for (int i = 0; i < 4; ++i) {
            int rr = outRowBase + i;
            if (rr < N)
                Outb[(size_t)(t >> 1) * SL + (size_t)rr * 32 + (t & 1) * 16 + m] =
                    f2bf(acc[t][i] * di[i]);
        }
}

// ---- bf16 GEMM: z (row-major, K=128) -> bufH (sliced, M_ cols) ----
template <int M_>
__global__ __launch_bounds__(256) void k_gemmb(
        const unsigned short* __restrict__ A, const unsigned short* __restrict__ Wt,
        const int* __restrict__ deg, unsigned short* __restrict__ Outb, int N) {
    constexpr int K = 128;
    constexpr int NT = M_ / 16;
    int tid = threadIdx.x;
    int lane = tid & 63, wave = tid >> 6;
    int m = lane & 15, quad = lane >> 4;
    int rowA = blockIdx.x * 64 + wave * 16 + m;    // grid exactly 782
    int rA = min(rowA, N - 1);

    bf16x8 afr[4];
#pragma unroll
    for (int s = 0; s < 4; ++s)
        afr[s] = *(const bf16x8*)(A + (size_t)rA * K + quad * 8 + s * 32);

    f32x4 acc[NT];
#pragma unroll
    for (int t = 0; t < NT; ++t) { acc[t][0] = 0.f; acc[t][1] = 0.f; acc[t][2] = 0.f; acc[t][3] = 0.f; }
#pragma unroll
    for (int t = 0; t < NT; ++t) {
        const unsigned short* wp = Wt + (size_t)(t * 16 + m) * K + quad * 8;
#pragma unroll
        for (int s = 0; s < 4; ++s) {
            bf16x8 bfr = *(const bf16x8*)(wp + s * 32);
            acc[t] = __builtin_amdgcn_mfma_f32_16x16x32_bf16(afr[s], bfr, acc[t], 0, 0, 0);
        }
    }

    int outRowBase = blockIdx.x * 64 + wave * 16 + quad * 4;
    float di[4];
#pragma unroll
    for (int i = 0; i < 4; ++i) di[i] = rsqrtf((float)deg[min(outRowBase + i, N - 1)] + 1.0f);
#pragma unroll
    for (int t = 0; t < NT; ++t)
#pragma unroll
        for (int i = 0; i < 4; ++i) {
            int rr = outRowBase + i;
            if (rr < N)
                Outb[(size_t)(t >> 1) * SL + (size_t)rr * 32 + (t & 1) * 16 + m] =
                    f2bf(acc[t][i] * di[i]);
        }
}

// ---- R22 sliced agg, XCD-PINNED: z[:, 32p:32p+32] = act(dinv*agg + b) ----
// blockIdx -> XCD is round-robin (%8, measured m09/m157). Mapping: block
// (slice p, tile i) at blockIdx = (i/TPX)*8 + p*TPX + i%TPX, TPX = 8/NS
// XCDs per slice -> each XCD gathers from ONE 3.2MB slice (< 4MB L2).
// Lane = (r4 = lane>>4 row-of-4, c16 = lane&15 dim-pair). perm32 colp:
// lane's 8 slot-indices = ONE u16x8 NT-load; 8 independent dword gathers
// cover all 32 logical slots mask-free (pads read zero row). Reduce = 2
// shfl levels x 2 accs. Tail deg>31: physical slots 32..63 (also padded).
// colp/deg NT-loads + z NT-store keep streams from evicting the slice.
template <int NS, bool RELU>
__global__ __launch_bounds__(256) void k_aggs(
        const unsigned short* __restrict__ hsl, const int* __restrict__ deg,
        const unsigned short* __restrict__ colp, const float* __restrict__ bias,
        unsigned short* __restrict__ z) {
    constexpr int ZW = NS * 32;
    constexpr int TPX = 8 / NS;
    int B = blockIdx.x;
    int x = B & 7, kk = B >> 3;
    int p = x / TPX;
    int i = kk * TPX + (x % TPX);
    if (i >= 3125) return;                       // grid 12504 (NS=4) / 6256 (NS=2)
    int tid = threadIdx.x;
    int wave = tid >> 6, lane = tid & 63;
    int c16 = lane & 15, r4 = lane >> 4;
    int nodeB = i * 16 + wave * 4;
    const unsigned short* hp = hsl + (size_t)p * SL + c16 * 2;

    i32x4 dg = __builtin_nontemporal_load((const i32x4*)(deg + nodeB));
    int dgv[4] = {dg[0], dg[1], dg[2], dg[3]};

    float2 bv = *(const float2*)(bias + p * 32 + c16 * 2);

    u16x8 sl[4];
#pragma unroll
    for (int t = 0; t < 4; ++t)
        sl[t] = __builtin_nontemporal_load(
            (const u16x8*)(colp + (unsigned)(nodeB + t) * SLOTS + r4 * 8));

#pragma unroll
    for (int t = 0; t < 4; ++t) {
        unsigned int v[8];
#pragma unroll
        for (int b = 0; b < 8; ++b)
            v[b] = *(const unsigned int*)(hp + (unsigned)sl[t][b] * 32);
        float a0 = 0.f, a1 = 0.f;
#pragma unroll
        for (int b = 0; b < 8; ++b) { a0 += bflo(v[b]); a1 += bfhi(v[b]); }
        if (dgv[t] > 31) {      // rare tail: physical slots 32..63
#pragma unroll
            for (int b = 0; b < 8; ++b) {
                unsigned int ix =
                    colp[(unsigned)(nodeB + t) * SLOTS + 32 + b * 4 + r4];
                unsigned int w = *(const unsigned int*)(hp + ix * 32);
                a0 += bflo(w); a1 += bfhi(w);
            }
        }
        a0 += __shfl_xor(a0, 16, 64); a0 += __shfl_xor(a0, 32, 64);
        a1 += __shfl_xor(a1, 16, 64); a1 += __shfl_xor(a1, 32, 64);
        if (r4 == 0) {
            float di = rsqrtf((float)dgv[t] + 1.0f);
            float o0 = di * a0 + bv.x, o1 = di * a1 + bv.y;
            if (RELU) { o0 = fmaxf(o0, 0.f); o1 = fmaxf(o1, 0.f); }
            unsigned int pk = (unsigned int)f2bf(o0) | ((unsigned int)f2bf(o1) << 16);
            __builtin_nontemporal_store(
                pk, (unsigned int*)(z + (size_t)(nodeB + t) * ZW + p * 32 + c16 * 2));
        }
    }
}

// ---- decode: out[e] = dot(z[ls[e]], z[ld[e]]) over 64 dims, z bf16 ----
__global__ __launch_bounds__(256) void k_decode(
        const unsigned short* __restrict__ z, const int* __restrict__ ls,
        const int* __restrict__ ld, float* __restrict__ out, int nl) {
    int tid = threadIdx.x;
    int lane = tid & 63, wave = tid >> 6;
    int g = lane >> 3, c = lane & 7;
    int e = (blockIdx.x * 4 + wave) * 4 + (g >> 1);   // grid exactly 6250
    int row = (g & 1) ? ld[e] : ls[e];
    u32x4 v = *(const u32x4*)(z + (size_t)row * 64 + c * 8);
    u32x4 w;
#pragma unroll
    for (int k = 0; k < 4; ++k) w[k] = (unsigned int)__shfl_xor((int)v[k], 8, 64);
    float p = 0.f;
#pragma unroll
    for (int k = 0; k < 4; ++k)
        p += bflo(v[k]) * bflo(w[k]) + bfhi(v[k]) * bfhi(w[k]);
    p += __shfl_xor(p, 1, 64);
    p += __shfl_xor(p, 2, 64);
    p += __shfl_xor(p, 4, 64);
    if ((lane & 15) == 0) out[e] = p;   // lane in {0,16,32,48}: g even, c==0
}

// ================= launcher =================

static inline size_t align256(size_t x) { return (x + 255) & ~(size_t)255; }

extern "C" void kernel_launch(void* const* d_in, const int* in_sizes, int n_in,
                              void* d_out, int out_size, void* d_ws, size_t ws_size,
                              hipStream_t stream) {
    const float* x  = (const float*)d_in[0];
    const int*   ei = (const int*)d_in[1];    // [2][NE]: row0=src, row1=dst
    const int*   li = (const int*)d_in[2];    // [2][NL]
    const float* W1 = (const float*)d_in[3];
    const float* b1 = (const float*)d_in[4];
    const float* W2 = (const float*)d_in[5];
    const float* b2 = (const float*)d_in[6];
    const float* W3 = (const float*)d_in[7];
    const float* b3 = (const float*)d_in[8];
    float* out = (float*)d_out;

    const int* src = ei;
    const int* dst = ei + NE;
    const int* ls = li;
    const int* ld = li + NL;

    // workspace carve-up (~43 MB)
    char* ws = (char*)d_ws;
    size_t off = 0;
    int* deg    = (int*)(ws + off); off += align256(NN * 4);
    int* cursor = (int*)(ws + off); off += align256(NB * 4);
    unsigned int* binbuf = (unsigned int*)(ws + off); off += align256((size_t)NB * BCAP * 4);
    unsigned short* colp = (unsigned short*)(ws + off); off += align256((size_t)NN * SLOTS * 2);
    unsigned short* Wtb  = (unsigned short*)(ws + off); off += align256(40960 * 2);
    unsigned short* bufH = (unsigned short*)(ws + off); off += align256((size_t)4 * SL * 2);
    unsigned short* bufZ1 = (unsigned short*)(ws + off); off += align256((size_t)NN * 128 * 2);
    unsigned short* bufZZ = (unsigned short*)(ws + off); off += align256((size_t)NN * 64 * 2);

    // ---- CSR build + W prep (+ zero per-slice pad rows of bufH) ----
    k_wprep<<<160, 256, 0, stream>>>(W1, W2, W3, Wtb, cursor, bufH);
    k_bin<<<391, 256, 0, stream>>>(src, dst, cursor, binbuf);
    k_csr<<<NB, 256, 0, stream>>>(binbuf, cursor, deg, colp);

    // ---- layer 1: h1 = dinv * x@W1 (sliced) ----
    k_gemm1<<<782, 256, 0, stream>>>(x, Wtb, deg, bufH, NN);
    // ---- agg1: z1 = relu(dinv*agg(h1) + b1), XCD-pinned sliced gather ----
    k_aggs<4, true><<<12504, 256, 0, stream>>>(bufH, deg, colp, b1, bufZ1);
    // ---- layer 2: h2 = dinv * z1@W2 (sliced) ----
    k_gemmb<128><<<782, 256, 0, stream>>>(bufZ1, Wtb + 16384, deg, bufH, NN);
    // ---- agg2: z2 = relu(dinv*agg(h2) + b2) ----
    k_aggs<4, true><<<12504, 256, 0, stream>>>(bufH, deg, colp, b2, bufZ1);
    // ---- layer 3: h3 = dinv * z2@W3 (2 slices) ----
    k_gemmb<64><<<782, 256, 0, stream>>>(bufZ1, Wtb + 32768, deg, bufH, NN);
    // ---- agg3: z = dinv*agg(h3) + b3 (no relu) ----
    k_aggs<2, false><<<6256, 256, 0, stream>>>(bufH, deg, colp, b3, bufZZ);
    // ---- decode ----
    k_decode<<<6250, 256, 0, stream>>>(bufZZ, ls, ld, out, NL);
}

// Round 12
// 233.312 us; speedup vs baseline: 1.5172x; 1.2428x over previous
//
#include <hip/hip_runtime.h>
#include <hip/hip_bf16.h>
#include <stdint.h>

// Problem constants (match reference)
#define NN 50000      // nodes
#define NE 800000     // edges
#define NL 100000     // label edges
#define SLOTS 64      // padded-CSR slots/node (incl. appended self-loop)
#define PADROW 50000  // dedicated all-zero row index in every h-buffer

// Bucketed CSR build (R7: direct scatter was line-bound)
#define NB 196        // dst-range buckets: bucket = dst >> 8 (256 nodes each)
#define BSH 8
#define BCAP 5376     // edges/bucket capacity; mean 4082 -> +20 sigma

typedef __attribute__((ext_vector_type(8))) short bf16x8;   // MFMA A/B frag
typedef __attribute__((ext_vector_type(4))) float f32x4;    // MFMA C/D frag
typedef __attribute__((ext_vector_type(4))) unsigned int u32x4;
typedef __attribute__((ext_vector_type(2))) unsigned int u32x2;
typedef __attribute__((ext_vector_type(8))) unsigned short u16x8;

__device__ __forceinline__ float asf(unsigned int u) {
    union { unsigned int i; float f; } c; c.i = u; return c.f;
}
__device__ __forceinline__ float bflo(unsigned int x) { return asf(x << 16); }
__device__ __forceinline__ float bfhi(unsigned int x) { return asf(x & 0xffff0000u); }
__device__ __forceinline__ unsigned short f2bf(float f) {
    union { float f; unsigned int i; } c; c.f = f;
    unsigned int u = c.i + (0x7fffu + ((c.i >> 16) & 1u));
    return (unsigned short)(u >> 16);
}

// ---- P0: W transpose+convert to bf16 Wt[n][k]; zero cursors + pad rows ----
__global__ void k_wprep(const float* __restrict__ W1, const float* __restrict__ W2,
                        const float* __restrict__ W3, unsigned short* __restrict__ Wt,
                        int* __restrict__ cursor, unsigned int* __restrict__ padA,
                        unsigned int* __restrict__ padB) {
    int idx = blockIdx.x * 256 + threadIdx.x;   // grid exactly 160
    if (idx < NB) cursor[idx] = 0;
    if (idx < 64) padA[idx] = 0;
    else if (idx < 128) padB[idx - 64] = 0;
    const float* W; unsigned short* O; int base, Mloc;
    if (idx < 16384)      { W = W1; O = Wt;         base = idx;         Mloc = 128; }
    else if (idx < 32768) { W = W2; O = Wt + 16384; base = idx - 16384; Mloc = 128; }
    else                  { W = W3; O = Wt + 32768; base = idx - 32768; Mloc = 64;  }
    int n = base >> 7, k = base & 127;
    O[base] = f2bf(W[k * Mloc + n]);
}

// ---- P1: bin edges by dst range (LDS histogram -> packed NT writes) ----
__global__ __launch_bounds__(256) void k_bin(
        const int* __restrict__ src, const int* __restrict__ dst,
        int* __restrict__ cursor, unsigned int* __restrict__ binbuf) {
    __shared__ int hcnt[NB];
    __shared__ int hbase[NB];
    __shared__ unsigned int epk[2048];
    int tid = threadIdx.x;
    if (tid < NB) hcnt[tid] = 0;
    __syncthreads();
    int e0 = blockIdx.x * 2048;                 // grid exactly 391
    int e1 = min(e0 + 2048, NE);
    for (int e = e0 + tid; e < e1; e += 256) {
        int d = dst[e], s = src[e];
        atomicAdd(&hcnt[d >> BSH], 1);
        epk[e - e0] = (unsigned int)s | ((unsigned int)d << 16);
    }
    __syncthreads();
    if (tid < NB) { hbase[tid] = atomicAdd(&cursor[tid], hcnt[tid]); hcnt[tid] = 0; }
    __syncthreads();
    for (int e = e0 + tid; e < e1; e += 256) {
        unsigned int pk = epk[e - e0];
        int b = (int)(pk >> 16) >> BSH;
        int p = hbase[b] + atomicAdd(&hcnt[b], 1);
        if (p < BCAP)
            __builtin_nontemporal_store(pk, &binbuf[(size_t)b * BCAP + p]);
    }
}

// ---- P2: per-bucket CSR build in LDS + coalesced flush ----
// Pad slots = PADROW (zero row -> mask-free gathers); self-loop appended at
// slot p=deg. Slots < 32 PERMUTED: logical p at physical 8*(p&3)+(p>>2), so
// lane-group g's physical [8g,8g+8): element k2 <-> logical 4*k2+g.
__global__ __launch_bounds__(256) void k_csr(
        const unsigned int* __restrict__ binbuf, const int* __restrict__ cursor,
        int* __restrict__ deg, unsigned short* __restrict__ colp) {
    __shared__ unsigned short lcol[256 * SLOTS];   // 32 KB
    __shared__ int ldeg[256];
    int tid = threadIdx.x;
    int blk = blockIdx.x;                          // grid exactly NB
    int base = blk << BSH;
    int nNodes = min(256, NN - base);
    ldeg[tid] = 0;
    const unsigned int fw = 0xC350C350u;           // 2x 50000
    u32x4 fill = {fw, fw, fw, fw};
    u32x4* lz = (u32x4*)lcol;
#pragma unroll
    for (int i = 0; i < 8; ++i) lz[i * 256 + tid] = fill;
    __syncthreads();
    int cnt = min(cursor[blk], BCAP);
    for (int e = tid; e < cnt; e += 256) {
        unsigned int pk = __builtin_nontemporal_load(&binbuf[(size_t)blk * BCAP + e]);
        int d = (int)(pk >> 16) - base;
        int p = atomicAdd(&ldeg[d], 1);
        if (p < SLOTS) {
            int pp = (p < 32) ? ((p & 3) * 8 + (p >> 2)) : p;
            lcol[d * SLOTS + pp] = (unsigned short)(pk & 0xffffu);
        }
    }
    __syncthreads();
    if (tid < nNodes) {
        int dv = ldeg[tid];
        deg[base + tid] = dv;
        if (dv < SLOTS) {                          // append self-loop slot
            int pp = (dv < 32) ? ((dv & 3) * 8 + (dv >> 2)) : dv;
            lcol[tid * SLOTS + pp] = (unsigned short)(base + tid);
        }
    }
    __syncthreads();
    u32x4* gout = (u32x4*)(colp + (size_t)base * SLOTS);
    const u32x4* lin = (const u32x4*)lcol;
    for (int i = tid; i < nNodes * 8; i += 256) gout[i] = lin[i];
}

// ---- layer-1 GEMM: x (fp32) -> bufA (h1). Rows >= NN untouched (pad!) ----
__global__ __launch_bounds__(256) void k_gemm1(
        const float* __restrict__ A, const unsigned short* __restrict__ Wt,
        const int* __restrict__ deg, unsigned short* __restrict__ Outb, int N) {
    constexpr int K = 128;
    constexpr int NT = 8;
    int tid = threadIdx.x;
    int lane = tid & 63, wave = tid >> 6;
    int m = lane & 15, quad = lane >> 4;
    int rowA = blockIdx.x * 64 + wave * 16 + m;    // grid exactly 782
    int rA = min(rowA, N - 1);

    bf16x8 afr[4];
    const float* p = A + (size_t)rA * K + quad * 8;
#pragma unroll
    for (int s = 0; s < 4; ++s) {
        float4 lo = *(const float4*)(p + s * 32);
        float4 hi = *(const float4*)(p + s * 32 + 4);
        bf16x8 r;
        r[0] = (short)f2bf(lo.x); r[1] = (short)f2bf(lo.y);
        r[2] = (short)f2bf(lo.z); r[3] = (short)f2bf(lo.w);
        r[4] = (short)f2bf(hi.x); r[5] = (short)f2bf(hi.y);
        r[6] = (short)f2bf(hi.z); r[7] = (short)f2bf(hi.w);
        afr[s] = r;
    }

    f32x4 acc[NT];
#pragma unroll
    for (int t = 0; t < NT; ++t) { acc[t][0] = 0.f; acc[t][1] = 0.f; acc[t][2] = 0.f; acc[t][3] = 0.f; }
#pragma unroll
    for (int t = 0; t < NT; ++t) {
        const unsigned short* wp = Wt + (size_t)(t * 16 + m) * K + quad * 8;
#pragma unroll
        for (int s = 0; s < 4; ++s) {
            bf16x8 bfr = *(const bf16x8*)(wp + s * 32);
            acc[t] = __builtin_amdgcn_mfma_f32_16x16x32_bf16(afr[s], bfr, acc[t], 0, 0, 0);
        }
    }

    int outRowBase = blockIdx.x * 64 + wave * 16 + quad * 4;
    float di[4];
#pragma unroll
    for (int i = 0; i < 4; ++i) di[i] = rsqrtf((float)deg[min(outRowBase + i, N - 1)] + 1.0f);
#pragma unroll
    for (int t = 0; t < NT; ++t)
#pragma unroll
        for (int i = 0; i < 4; ++i) {
            int rr = outRowBase + i;
            if (rr < N) Outb[(size_t)rr * 128 + t * 16 + m] = f2bf(acc[t][i] * di[i]);
        }
}

// ---- FUSED agg+gemm (R23: R16 structure, launch_bounds (256,6)) ----
// R16 post-mortem: (256,8) capped unified VGPR+AGPR at 64; compiler gave the
// gather phase ~32 arch VGPRs -> only ~2-3 of the 6 batch-A loads in flight.
// R23: (256,6) raises the cap to ~84. Gather-phase live state (vv[6]=24 +
// sl/sln=8 + acc=8 + addr ~20 = ~60) now fits WITHOUT spilling (unlike R17,
// which added a 2-node pipeline on top and spilled). 6 waves/SIMD with all
// 6 loads in flight ≈ 1.8x issue MLP vs R16. Everything else identical:
// depth-6 batch A (deg<=23, P=.96), batch B (2 loads), batch C (rare).
template <int M_>
__global__ __launch_bounds__(256, 6) void k_agg_gemm(
        const unsigned short* __restrict__ hs, const int* __restrict__ deg,
        const unsigned short* __restrict__ colp, const float* __restrict__ bias,
        const unsigned short* __restrict__ Wt, unsigned short* __restrict__ Outb) {
    constexpr int K = 128;          // agg feature width and gemm K
    constexpr int NT = M_ / 64;     // col tiles per wave: 128->2, 64->1
    __shared__ __align__(16) unsigned short As[16][136];
    int tid = threadIdx.x;
    int lane = tid & 63, wave = tid >> 6;
    int tileBase = blockIdx.x * 16;
    int g = lane >> 4, c = lane & 15;
    const unsigned short* hc = hs + c * 8;
    int nodeB = tileBase + wave * 4;

    int4 dg = *(const int4*)(deg + nodeB);         // 16B aligned
    int dgv[4] = {dg.x, dg.y, dg.z, dg.w};

    u16x8 sl = *(const u16x8*)(colp + (unsigned)nodeB * SLOTS + g * 8);

    // ---- agg phase: wave aggregates rows wave*4 .. wave*4+3 ----
#pragma unroll
    for (int t = 0; t < 4; ++t) {
        int node = nodeB + t;
        int su = min(dgv[t] + 1, SLOTS);           // slots incl. self

        u32x4 vv[6];
#pragma unroll
        for (int k2 = 0; k2 < 6; ++k2)
            vv[k2] = *(const u32x4*)(hc + (unsigned)sl[k2] * K);
        u16x8 sln = sl;
        if (t < 3) sln = *(const u16x8*)(colp + (unsigned)(node + 1) * SLOTS + g * 8);

        float acc[8];
#pragma unroll
        for (int k = 0; k < 8; ++k) acc[k] = 0.f;
#pragma unroll
        for (int k2 = 0; k2 < 6; ++k2)
#pragma unroll
            for (int k = 0; k < 4; ++k) {
                acc[2 * k]     += bflo(vv[k2][k]);
                acc[2 * k + 1] += bfhi(vv[k2][k]);
            }
        if (su > 24) {          // batch B: logical slots 24..31
            u32x4 w0 = *(const u32x4*)(hc + (unsigned)sl[6] * K);
            u32x4 w1 = *(const u32x4*)(hc + (unsigned)sl[7] * K);
#pragma unroll
            for (int k = 0; k < 4; ++k) {
                acc[2 * k]     += bflo(w0[k]) + bflo(w1[k]);
                acc[2 * k + 1] += bfhi(w0[k]) + bfhi(w1[k]);
            }
            if (su > 32) {      // batch C: physical slots 32..63 (identity)
                u16x8 s2 = *(const u16x8*)(colp + (unsigned)node * SLOTS + 32 + g * 8);
#pragma unroll
                for (int h = 0; h < 2; ++h) {
                    u32x4 x0 = *(const u32x4*)(hc + (unsigned)s2[4 * h + 0] * K);
                    u32x4 x1 = *(const u32x4*)(hc + (unsigned)s2[4 * h + 1] * K);
                    u32x4 x2 = *(const u32x4*)(hc + (unsigned)s2[4 * h + 2] * K);
                    u32x4 x3 = *(const u32x4*)(hc + (unsigned)s2[4 * h + 3] * K);
#pragma unroll
                    for (int k = 0; k < 4; ++k) {
                        acc[2 * k]     += bflo(x0[k]) + bflo(x1[k]) + bflo(x2[k]) + bflo(x3[k]);
                        acc[2 * k + 1] += bfhi(x0[k]) + bfhi(x1[k]) + bfhi(x2[k]) + bfhi(x3[k]);
                    }
                }
            }
        }
        sl = sln;

        // cross-group reduce: groups {0,1,2,3} hold partial sums of same dims
#pragma unroll
        for (int k = 0; k < 8; ++k) {
            acc[k] += __shfl_xor(acc[k], 16, 64);
            acc[k] += __shfl_xor(acc[k], 32, 64);
        }
        if (g == 0) {
            float di = rsqrtf((float)dgv[t] + 1.0f);
            const float4* bp = (const float4*)(bias + c * 8);
            float4 b0 = bp[0], b1 = bp[1];
            float bb[8] = {b0.x, b0.y, b0.z, b0.w, b1.x, b1.y, b1.z, b1.w};
            u32x4 pv;
#pragma unroll
            for (int k = 0; k < 4; ++k) {
                float o0 = fmaxf(di * acc[2 * k]     + bb[2 * k],     0.f);
                float o1 = fmaxf(di * acc[2 * k + 1] + bb[2 * k + 1], 0.f);
                pv[k] = (unsigned int)f2bf(o0) | ((unsigned int)f2bf(o1) << 16);
            }
            *(u32x4*)&As[wave * 4 + t][c * 8] = pv;   // 16B aligned
        }
    }
    __syncthreads();

    // ---- gemm phase: 16 rows x M_ cols from LDS A-tile ----
    int m = lane & 15, quad = lane >> 4;
    bf16x8 afr[4];
#pragma unroll
    for (int s = 0; s < 4; ++s)
        afr[s] = *(const bf16x8*)&As[m][s * 32 + quad * 8];

    f32x4 gacc[NT];
#pragma unroll
    for (int t = 0; t < NT; ++t) { gacc[t][0] = 0.f; gacc[t][1] = 0.f; gacc[t][2] = 0.f; gacc[t][3] = 0.f; }
#pragma unroll
    for (int t = 0; t < NT; ++t) {
        int ct = wave * NT + t;     // col tile 0..M_/16-1
        const unsigned short* wp = Wt + (size_t)(ct * 16 + m) * K + quad * 8;
#pragma unroll
        for (int s = 0; s < 4; ++s) {
            bf16x8 bfr = *(const bf16x8*)(wp + s * 32);
            gacc[t] = __builtin_amdgcn_mfma_f32_16x16x32_bf16(afr[s], bfr, gacc[t], 0, 0, 0);
        }
    }

    int rowBase = tileBase + quad * 4;
    int4 dg2 = *(const int4*)(deg + rowBase);
    int dgw[4] = {dg2.x, dg2.y, dg2.z, dg2.w};
    float di[4];
#pragma unroll
    for (int i = 0; i < 4; ++i) di[i] = rsqrtf((float)dgw[i] + 1.0f);
#pragma unroll
    for (int t = 0; t < NT; ++t) {
        int ct = wave * NT + t;
#pragma unroll
        for (int i = 0; i < 4; ++i)
            Outb[(size_t)(rowBase + i) * M_ + ct * 16 + m] = f2bf(gacc[t][i] * di[i]);
    }
}

// ---- final aggregation (F=64, no relu) -> z (bf16) ----
// R16 version: depth-6 mask-free + cond B/C.
__global__ __launch_bounds__(256, 8) void k_agg64(
        const unsigned short* __restrict__ hs, const int* __restrict__ deg,
        const unsigned short* __restrict__ colp, const float* __restrict__ bias,
        unsigned short* __restrict__ out, int n) {
    int tid = threadIdx.x;
    int wave = tid >> 6, lane = tid & 63;
    int node = blockIdx.x * 4 + wave;               // grid exactly 12500
    int g = lane >> 4, c = lane & 15;
    const unsigned short* hc = hs + c * 4;

    int degv = deg[node];
    int su = min(degv + 1, SLOTS);
    u16x8 sl = *(const u16x8*)(colp + (unsigned)node * SLOTS + g * 8);

    u32x2 vv[6];
#pragma unroll
    for (int k2 = 0; k2 < 6; ++k2)
        vv[k2] = *(const u32x2*)(hc + (unsigned)sl[k2] * 64);

    float acc[4] = {0.f, 0.f, 0.f, 0.f};
#pragma unroll
    for (int k2 = 0; k2 < 6; ++k2)
#pragma unroll
        for (int k = 0; k < 2; ++k) {
            acc[2 * k]     += bflo(vv[k2][k]);
            acc[2 * k + 1] += bfhi(vv[k2][k]);
        }
    if (su > 24) {              // batch B: logical slots 24..31
        u32x2 w0 = *(const u32x2*)(hc + (unsigned)sl[6] * 64);
        u32x2 w1 = *(const u32x2*)(hc + (unsigned)sl[7] * 64);
#pragma unroll
        for (int k = 0; k < 2; ++k) {
            acc[2 * k]     += bflo(w0[k]) + bflo(w1[k]);
            acc[2 * k + 1] += bfhi(w0[k]) + bfhi(w1[k]);
        }
        if (su > 32) {          // batch C: physical slots 32..63
            u16x8 s2 = *(const u16x8*)(colp + (unsigned)node * SLOTS + 32 + g * 8);
#pragma unroll
            for (int h = 0; h < 2; ++h) {
                u32x2 x0 = *(const u32x2*)(hc + (unsigned)s2[4 * h + 0] * 64);
                u32x2 x1 = *(const u32x2*)(hc + (unsigned)s2[4 * h + 1] * 64);
                u32x2 x2 = *(const u32x2*)(hc + (unsigned)s2[4 * h + 2] * 64);
                u32x2 x3 = *(const u32x2*)(hc + (unsigned)s2[4 * h + 3] * 64);
#pragma unroll
                for (int k = 0; k < 2; ++k) {
                    acc[2 * k]     += bflo(x0[k]) + bflo(x1[k]) + bflo(x2[k]) + bflo(x3[k]);
                    acc[2 * k + 1] += bfhi(x0[k]) + bfhi(x1[k]) + bfhi(x2[k]) + bfhi(x3[k]);
                }
            }
        }
    }
#pragma unroll
    for (int k = 0; k < 4; ++k) {
        acc[k] += __shfl_xor(acc[k], 16, 64);
        acc[k] += __shfl_xor(acc[k], 32, 64);
    }
    if (g == 0) {
        float di = rsqrtf((float)degv + 1.0f);
        float4 bb = *(const float4*)(bias + c * 4);
        u32x2 pv;
        pv[0] = (unsigned int)f2bf(di * acc[0] + bb.x) |
                ((unsigned int)f2bf(di * acc[1] + bb.y) << 16);
        pv[1] = (unsigned int)f2bf(di * acc[2] + bb.z) |
                ((unsigned int)f2bf(di * acc[3] + bb.w) << 16);
        *(u32x2*)(out + (size_t)node * 64 + c * 4) = pv;
    }
}

// ---- decode: out[e] = dot(z[ls[e]], z[ld[e]]) over 64 dims, z bf16 ----
__global__ __launch_bounds__(256) void k_decode(
        const unsigned short* __restrict__ z, const int* __restrict__ ls,
        const int* __restrict__ ld, float* __restrict__ out, int nl) {
    int tid = threadIdx.x;
    int lane = tid & 63, wave = tid >> 6;
    int g = lane >> 3, c = lane & 7;
    int e = (blockIdx.x * 4 + wave) * 4 + (g >> 1);   // grid exactly 6250
    int row = (g & 1) ? ld[e] : ls[e];
    u32x4 v = *(const u32x4*)(z + (size_t)row * 64 + c * 8);
    u32x4 w;
#pragma unroll
    for (int k = 0; k < 4; ++k) w[k] = (unsigned int)__shfl_xor((int)v[k], 8, 64);
    float p = 0.f;
#pragma unroll
    for (int k = 0; k < 4; ++k)
        p += bflo(v[k]) * bflo(w[k]) + bfhi(v[k]) * bfhi(w[k]);
    p += __shfl_xor(p, 1, 64);
    p += __shfl_xor(p, 2, 64);
    p += __shfl_xor(p, 4, 64);
    if ((lane & 15) == 0) out[e] = p;   // lane in {0,16,32,48}: g even, c==0
}

// ================= launcher =================

static inline size_t align256(size_t x) { return (x + 255) & ~(size_t)255; }

extern "C" void kernel_launch(void* const* d_in, const int* in_sizes, int n_in,
                              void* d_out, int out_size, void* d_ws, size_t ws_size,
                              hipStream_t stream) {
    const float* x  = (const float*)d_in[0];
    const int*   ei = (const int*)d_in[1];    // [2][NE]: row0=src, row1=dst
    const int*   li = (const int*)d_in[2];    // [2][NL]
    const float* W1 = (const float*)d_in[3];
    const float* b1 = (const float*)d_in[4];
    const float* W2 = (const float*)d_in[5];
    const float* b2 = (const float*)d_in[6];
    const float* W3 = (const float*)d_in[7];
    const float* b3 = (const float*)d_in[8];
    float* out = (float*)d_out;

    const int* src = ei;
    const int* dst = ei + NE;
    const int* ls = li;
    const int* ld = li + NL;

    // workspace carve-up (~43 MB)
    char* ws = (char*)d_ws;
    size_t off = 0;
    int* deg    = (int*)(ws + off); off += align256(NN * 4);
    int* cursor = (int*)(ws + off); off += align256(NB * 4);
    unsigned int* binbuf = (unsigned int*)(ws + off); off += align256((size_t)NB * BCAP * 4);
    unsigned short* colp = (unsigned short*)(ws + off); off += align256((size_t)NN * SLOTS * 2);
    unsigned short* Wtb  = (unsigned short*)(ws + off); off += align256(40960 * 2);
    // bufA: h1 (128-wide, rows 0..NN-1) + pad row at 50000.
    // h3 (64-wide) = bufA upper half; its pad row 50000 aliases bufA's.
    unsigned short* bufA = (unsigned short*)(ws + off); off += align256(((size_t)NN * 128 + 128) * 2);
    unsigned short* bufB = (unsigned short*)(ws + off); off += align256(((size_t)NN * 128 + 128) * 2);
    unsigned short* bufZ = (unsigned short*)(ws + off); off += align256((size_t)NN * 64 * 2);
    unsigned short* h3 = bufA + (size_t)25000 * 128;

    // ---- CSR build + W prep (+ zero pad rows) ----
    k_wprep<<<160, 256, 0, stream>>>(W1, W2, W3, Wtb, cursor,
                                     (unsigned int*)(bufA + (size_t)PADROW * 128),
                                     (unsigned int*)(bufB + (size_t)PADROW * 128));
    k_bin<<<391, 256, 0, stream>>>(src, dst, cursor, binbuf);
    k_csr<<<NB, 256, 0, stream>>>(binbuf, cursor, deg, colp);

    // ---- layer 1 GEMM: x -> bufA (h1 = dinv * x@W1, bf16) ----
    k_gemm1<<<782, 256, 0, stream>>>(x, Wtb, deg, bufA, NN);
    // ---- fused agg1(+b1,relu) + gemm2: bufA -> bufB (h2) ----
    k_agg_gemm<128><<<3125, 256, 0, stream>>>(bufA, deg, colp, b1, Wtb + 16384, bufB);
    // ---- fused agg2(+b2,relu) + gemm3: bufB -> h3 (64-wide) ----
    k_agg_gemm<64><<<3125, 256, 0, stream>>>(bufB, deg, colp, b2, Wtb + 32768, h3);
    // ---- agg3(+b3, no relu): h3 -> bufZ (z) ----
    k_agg64<<<12500, 256, 0, stream>>>(h3, deg, colp, b3, bufZ, NN);
    // ---- decode ----
    k_decode<<<6250, 256, 0, stream>>>(bufZ, ls, ld, out, NL);
}